// Round 8
// baseline (187.624 us; speedup 1.0000x reference)
//
#include <hip/hip_runtime.h>
#include <hip/hip_bf16.h>

// Problem constants
#define BATCH 2
#define SEQ   4096
#define DIM   512
#define NHEAD 8
#define HDIM  64
#define ROWS  (BATCH*SEQ)   // 8192

typedef float  fx4   __attribute__((ext_vector_type(4)));
typedef __bf16 bf16x8 __attribute__((ext_vector_type(8)));
typedef unsigned short ushort_t;
typedef unsigned short usx4 __attribute__((ext_vector_type(4)));
typedef unsigned short usx8 __attribute__((ext_vector_type(8)));

static __device__ __forceinline__ float b2f(ushort_t v) {
    union { unsigned int u; float f; } c; c.u = ((unsigned int)v) << 16; return c.f;
}
static __device__ __forceinline__ ushort_t f2b(float f) {
    union { float f; unsigned int u; } c; c.f = f;
    unsigned int u = c.u;
    unsigned int r = (u + 0x7FFFu + ((u >> 16) & 1u)) >> 16;
    return (ushort_t)r;
}
static __device__ __forceinline__ void gload16(const ushort_t* g, ushort_t* l) {
    __builtin_amdgcn_global_load_lds(
        (const __attribute__((address_space(1))) unsigned int*)g,
        (__attribute__((address_space(3))) unsigned int*)l, 16, 0, 0);
}

// ---------------- prep: transpose 4 weights (y<4) + cast x -> bf16 (y>=4) ----------------
__global__ __launch_bounds__(256) void prep_kernel(
    const float* __restrict__ val, ushort_t* __restrict__ xb,
    const float* __restrict__ W0, const float* __restrict__ W1,
    const float* __restrict__ W2, const float* __restrict__ W3,
    ushort_t* __restrict__ T0, ushort_t* __restrict__ T1,
    ushort_t* __restrict__ T2, ushort_t* __restrict__ T3) {

    const int tid = threadIdx.x;
    if (blockIdx.y >= 4) {
        const int bid = blockIdx.x + 64 * (blockIdx.y - 4);
        const int stride = 256 * 256 * 4;
        for (int i = (bid * 256 + tid) * 4; i < ROWS * 512; i += stride) {
            fx4 v = *(const fx4*)(val + i);
            usx4 o; o.x = f2b(v.x); o.y = f2b(v.y); o.z = f2b(v.z); o.w = f2b(v.w);
            *(usx4*)(xb + i) = o;
        }
        return;
    }
    const float* W; ushort_t* WT;
    switch (blockIdx.y) {
        case 0: W = W0; WT = T0; break;
        case 1: W = W1; WT = T1; break;
        case 2: W = W2; WT = T2; break;
        default: W = W3; WT = T3; break;
    }
    __shared__ float tile[64][65];
    int r0 = (blockIdx.x & 7) * 64;
    int c0 = (blockIdx.x >> 3) * 64;
    for (int idx = tid; idx < 4096; idx += 256) {
        int rr = idx >> 6, cc = idx & 63;
        tile[rr][cc] = W[(c0 + rr) * 512 + (r0 + cc)];
    }
    __syncthreads();
    for (int idx = tid; idx < 4096; idx += 256) {
        int rr = idx >> 6, cc = idx & 63;
        WT[(size_t)(r0 + rr) * 512 + (c0 + cc)] = f2b(tile[cc][rr]);
    }
}

// ---------------- bf16 QKV GEMM (R3-best): 128x128 tile, BK=32 ----------------
// grid: (M/128, 4, 3). z==2 writes transposed per head: Vt[bh][d][s].
__global__ __launch_bounds__(256) void gemm128_kernel(
    const ushort_t* __restrict__ A,
    const ushort_t* __restrict__ BT0, const ushort_t* __restrict__ BT1, const ushort_t* __restrict__ BT2,
    const float* __restrict__ b0, const float* __restrict__ b1, const float* __restrict__ b2,
    ushort_t* __restrict__ C0, ushort_t* __restrict__ C1, ushort_t* __restrict__ C2) {

    const ushort_t* BT; const float* bias; ushort_t* C;
    if (blockIdx.z == 0)      { BT = BT0; bias = b0; C = C0; }
    else if (blockIdx.z == 1) { BT = BT1; bias = b1; C = C1; }
    else                      { BT = BT2; bias = b2; C = C2; }

    __shared__ ushort_t As[128 * 32];
    __shared__ ushort_t Bs[128 * 32];

    const int tid  = threadIdx.x;
    const int wave = tid >> 6;
    const int lane = tid & 63;
    const int lm   = lane & 15;
    const int quad = lane >> 4;
    const int wm   = wave >> 1;
    const int wn   = wave & 1;

    const int m0t = blockIdx.x * 128;
    const int n0t = blockIdx.y * 128;

    const int srow = tid >> 2, sgc = tid & 3;
    const ushort_t* ga0 = A  + (size_t)(m0t + srow) * 512 + sgc * 8;
    const ushort_t* ga1 = ga0 + (size_t)64 * 512;
    const ushort_t* gb0 = BT + (size_t)(n0t + srow) * 512 + sgc * 8;
    const ushort_t* gb1 = gb0 + (size_t)64 * 512;
    ushort_t* la0 = As + tid * 8;
    ushort_t* la1 = As + (tid + 256) * 8;
    ushort_t* lb0 = Bs + tid * 8;
    ushort_t* lb1 = Bs + (tid + 256) * 8;

    const int aoff = (wm * 64 + lm) * 32 + quad * 8;
    const int boff = (wn * 64 + lm) * 32 + quad * 8;

    fx4 acc[4][4];
    #pragma unroll
    for (int i = 0; i < 4; ++i)
        #pragma unroll
        for (int j = 0; j < 4; ++j) acc[i][j] = 0;

    for (int k0 = 0; k0 < 512; k0 += 32) {
        __syncthreads();
        gload16(ga0 + k0, la0);
        gload16(ga1 + k0, la1);
        gload16(gb0 + k0, lb0);
        gload16(gb1 + k0, lb1);
        __syncthreads();

        bf16x8 af[4], bfr[4];
        #pragma unroll
        for (int ms = 0; ms < 4; ++ms) af[ms]  = *(const bf16x8*)&As[aoff + ms * 512];
        #pragma unroll
        for (int ns = 0; ns < 4; ++ns) bfr[ns] = *(const bf16x8*)&Bs[boff + ns * 512];
        #pragma unroll
        for (int ms = 0; ms < 4; ++ms)
            #pragma unroll
            for (int ns = 0; ns < 4; ++ns)
                acc[ms][ns] = __builtin_amdgcn_mfma_f32_16x16x32_bf16(af[ms], bfr[ns], acc[ms][ns], 0, 0, 0);
    }

    const int crow0 = m0t + wm * 64 + quad * 4;
    const int ccol0 = n0t + wn * 64 + lm;

    if (blockIdx.z == 2) {
        #pragma unroll
        for (int ns = 0; ns < 4; ++ns) {
            int col = ccol0 + ns * 16;
            int h = col >> 6, d = col & 63;
            float bv = bias[col];
            #pragma unroll
            for (int ms = 0; ms < 4; ++ms) {
                int m = crow0 + ms * 16;
                int bb = m >> 12, s0 = m & 4095;
                usx4 o;
                o.x = f2b(acc[ms][ns][0] + bv); o.y = f2b(acc[ms][ns][1] + bv);
                o.z = f2b(acc[ms][ns][2] + bv); o.w = f2b(acc[ms][ns][3] + bv);
                *(usx4*)(C + (((size_t)(bb * 8 + h) * 64 + d) * 4096 + s0)) = o;
            }
        }
    } else {
        #pragma unroll
        for (int ns = 0; ns < 4; ++ns) {
            int col = ccol0 + ns * 16;
            float bv = bias[col];
            #pragma unroll
            for (int ms = 0; ms < 4; ++ms) {
                #pragma unroll
                for (int r = 0; r < 4; ++r) {
                    C[(size_t)(crow0 + ms * 16 + r) * 512 + col] = f2b(acc[ms][ns][r] + bv);
                }
            }
        }
    }
}

// ---------------- O-proj GEMM: 128x64 tile (grid 512 = 2 blocks/CU) ----------------
__global__ __launch_bounds__(256) void gemm_n64_kernel(
    const ushort_t* __restrict__ A, const ushort_t* __restrict__ BT,
    const float* __restrict__ bias, ushort_t* __restrict__ C) {

    __shared__ ushort_t As[128 * 32];
    __shared__ ushort_t Bs[64 * 32];

    const int tid  = threadIdx.x;
    const int wave = tid >> 6;
    const int lane = tid & 63;
    const int lm   = lane & 15;
    const int quad = lane >> 4;
    const int wm   = wave >> 1;
    const int wn   = wave & 1;

    const int m0t = blockIdx.x * 128;
    const int n0t = blockIdx.y * 64;

    const int srow = tid >> 2, sgc = tid & 3;
    const ushort_t* ga0 = A  + (size_t)(m0t + srow) * 512 + sgc * 8;
    const ushort_t* ga1 = ga0 + (size_t)64 * 512;
    const ushort_t* gb  = BT + (size_t)(n0t + srow) * 512 + sgc * 8;

    const int aoff = (wm * 64 + lm) * 32 + quad * 8;
    const int boff = (wn * 32 + lm) * 32 + quad * 8;

    fx4 acc[4][2];
    #pragma unroll
    for (int i = 0; i < 4; ++i) { acc[i][0] = 0; acc[i][1] = 0; }

    for (int k0 = 0; k0 < 512; k0 += 32) {
        __syncthreads();
        gload16(ga0 + k0, As + tid * 8);
        gload16(ga1 + k0, As + (tid + 256) * 8);
        gload16(gb + k0, Bs + tid * 8);
        __syncthreads();

        bf16x8 af[4], bfr[2];
        #pragma unroll
        for (int ms = 0; ms < 4; ++ms) af[ms]  = *(const bf16x8*)&As[aoff + ms * 512];
        #pragma unroll
        for (int ns = 0; ns < 2; ++ns) bfr[ns] = *(const bf16x8*)&Bs[boff + ns * 512];
        #pragma unroll
        for (int ms = 0; ms < 4; ++ms)
            #pragma unroll
            for (int ns = 0; ns < 2; ++ns)
                acc[ms][ns] = __builtin_amdgcn_mfma_f32_16x16x32_bf16(af[ms], bfr[ns], acc[ms][ns], 0, 0, 0);
    }

    const int crow0 = m0t + wm * 64 + quad * 4;
    const int ccol0 = n0t + wn * 32 + lm;
    #pragma unroll
    for (int ns = 0; ns < 2; ++ns) {
        int col = ccol0 + ns * 16;
        float bv = bias[col];
        #pragma unroll
        for (int ms = 0; ms < 4; ++ms)
            #pragma unroll
            for (int r = 0; r < 4; ++r)
                C[(size_t)(crow0 + ms * 16 + r) * 512 + col] = f2b(acc[ms][ns][r] + bv);
    }
}

// ---------------- MFMA sliding-window attention (radius 256) ----------------
// grid: (SEQ/64, 16) = 1024 blocks, 256 threads = 4 waves.
// Wave = (query-half qh, tile-parity tp): 32 queries over half the K-tiles.
// Plain exp (no online max) => tile contributions are additive; partial (O,l)
// combined across tile-parities through LDS at the end.
__global__ __launch_bounds__(256, 4) void attn_mfma_kernel(
    const ushort_t* __restrict__ Qb, const ushort_t* __restrict__ Kb,
    const ushort_t* __restrict__ Vt, ushort_t* __restrict__ Ob) {

    // smem: K 8KB | V 8KB | P 4x(32x72)x2B = 18KB   (34.8KB total)
    __shared__ __align__(16) char smem[16384 + 18432];
    ushort_t* Klds = (ushort_t*)smem;
    ushort_t* Vlds = (ushort_t*)(smem + 8192);

    const int tid  = threadIdx.x;
    const int wave = tid >> 6;
    const int lane = tid & 63;
    const int lm   = lane & 15;
    const int quad = lane >> 4;
    const int qh   = wave & 1;    // query half
    const int tp   = wave >> 1;   // tile parity

    const int bh = blockIdx.y;
    const int b = bh >> 3, h = bh & 7;
    const int q0 = blockIdx.x * 64;
    const int qw = q0 + qh * 32;

    ushort_t* Pw = (ushort_t*)(smem + 16384) + wave * 2304;   // [32 q][72]

    // Q B-frags for the two 16q groups
    bf16x8 qf[2][2];
    #pragma unroll
    for (int qg = 0; qg < 2; ++qg) {
        const ushort_t* qp = Qb + ((size_t)(b * SEQ + qw + qg * 16 + lm)) * 512 + h * 64 + quad * 8;
        qf[qg][0] = *(const bf16x8*)qp;
        qf[qg][1] = *(const bf16x8*)(qp + 32);
    }

    int koff[2][4], voff[2][4];
    #pragma unroll
    for (int ks = 0; ks < 2; ++ks) {
        #pragma unroll
        for (int tn = 0; tn < 4; ++tn) {
            int key = tn * 16 + lm;
            koff[ks][tn] = key * 64 + (((ks * 4 + quad) ^ (key & 7)) * 8);
            int d = tn * 16 + lm;
            voff[ks][tn] = d * 64 + (((ks * 4 + quad) ^ (d & 7)) * 8);
        }
    }

    const int skey = tid >> 3;
    const int sdg  = tid & 7;
    const size_t kgbase = ((size_t)b * SEQ) * 512 + h * 64 + sdg * 8;
    const size_t vgbase = ((size_t)bh * 64) * 4096 + sdg * 8;
    const int l0 = skey * 64 + ((sdg ^ (skey & 7)) * 8);
    const int l1 = l0 + 32 * 64;

    const int klo = (q0 >= 256) ? 0 : ((256 - q0) >> 6);
    const int khi = min(8, (4288 - q0) >> 6);

    bf16x8 onesf;
    {
        __bf16 o = (lm == 0) ? (__bf16)1.0f : (__bf16)0.0f;
        #pragma unroll
        for (int j = 0; j < 8; ++j) onesf[j] = o;
    }

    fx4 oacc[2][4];
    #pragma unroll
    for (int qg = 0; qg < 2; ++qg)
        #pragma unroll
        for (int tn = 0; tn < 4; ++tn) oacc[qg][tn] = 0;
    fx4 lacc[2];
    lacc[0] = 0; lacc[1] = 0;

    usx8 kn0, kn1, vn0, vn1;
    {
        int ts = q0 - 256 + klo * 64;
        kn0 = *(const usx8*)(Kb + kgbase + (size_t)(ts + skey) * 512);
        kn1 = *(const usx8*)(Kb + kgbase + (size_t)(ts + skey + 32) * 512);
        vn0 = *(const usx8*)(Vt + vgbase + (size_t)skey * 4096 + ts);
        vn1 = *(const usx8*)(Vt + vgbase + (size_t)(skey + 32) * 4096 + ts);
    }

    for (int kt = klo; kt <= khi; ++kt) {
        const int ts = q0 - 256 + kt * 64;
        __syncthreads();
        *(usx8*)&Klds[l0] = kn0;
        *(usx8*)&Klds[l1] = kn1;
        *(usx8*)&Vlds[l0] = vn0;
        *(usx8*)&Vlds[l1] = vn1;
        __syncthreads();

        if (kt < khi) {   // prefetch next tile during compute
            int t2 = ts + 64;
            kn0 = *(const usx8*)(Kb + kgbase + (size_t)(t2 + skey) * 512);
            kn1 = *(const usx8*)(Kb + kgbase + (size_t)(t2 + skey + 32) * 512);
            vn0 = *(const usx8*)(Vt + vgbase + (size_t)skey * 4096 + t2);
            vn1 = *(const usx8*)(Vt + vgbase + (size_t)(skey + 32) * 4096 + t2);
        }

        if ((kt & 1) != tp) continue;   // this wave handles only its tile parity

        // S^T = K (64 keys) @ Q^T (2x16 q)
        bf16x8 kf[2][4];
        #pragma unroll
        for (int ks = 0; ks < 2; ++ks)
            #pragma unroll
            for (int tn = 0; tn < 4; ++tn)
                kf[ks][tn] = *(const bf16x8*)&Klds[koff[ks][tn]];

        #pragma unroll
        for (int qg = 0; qg < 2; ++qg) {
            fx4 sacc[4];
            sacc[0] = 0; sacc[1] = 0; sacc[2] = 0; sacc[3] = 0;
            #pragma unroll
            for (int ks = 0; ks < 2; ++ks) {
                bf16x8 q8 = qf[qg][ks];
                #pragma unroll
                for (int tn = 0; tn < 4; ++tn)
                    sacc[tn] = __builtin_amdgcn_mfma_f32_16x16x32_bf16(kf[ks][tn], q8, sacc[tn], 0, 0, 0);
            }
            const int qbase = qw + qg * 16;
            const bool edge = (ts < qbase - 241) || (ts > qbase + 193);
            const int qg_q = qbase + lm;
            #pragma unroll
            for (int tn = 0; tn < 4; ++tn) {
                usx4 pk;
                #pragma unroll
                for (int r = 0; r < 4; ++r) {
                    float p = __expf(sacc[tn][r] * 0.125f);
                    if (edge) {
                        int dlt = (ts + tn * 16 + quad * 4 + r) - qg_q;
                        p = (dlt <= 256 && dlt >= -256) ? p : 0.0f;
                    }
                    pk[r] = f2b(p);
                }
                *(usx4*)&Pw[(qg * 16 + lm) * 72 + tn * 16 + quad * 4] = pk;
            }
        }

        // O += P @ V ; l += P @ ones
        bf16x8 vf[2][4];
        #pragma unroll
        for (int ks = 0; ks < 2; ++ks)
            #pragma unroll
            for (int tn = 0; tn < 4; ++tn)
                vf[ks][tn] = *(const bf16x8*)&Vlds[voff[ks][tn]];
        #pragma unroll
        for (int qg = 0; qg < 2; ++qg) {
            #pragma unroll
            for (int ks = 0; ks < 2; ++ks) {
                bf16x8 ap = *(const bf16x8*)&Pw[(qg * 16 + lm) * 72 + ks * 32 + quad * 8];
                lacc[qg] = __builtin_amdgcn_mfma_f32_16x16x32_bf16(ap, onesf, lacc[qg], 0, 0, 0);
                #pragma unroll
                for (int tn = 0; tn < 4; ++tn)
                    oacc[qg][tn] = __builtin_amdgcn_mfma_f32_16x16x32_bf16(ap, vf[ks][tn], oacc[qg][tn], 0, 0, 0);
            }
        }
    }

    // combine the two tile-parities per query-half through LDS, then store
    __syncthreads();
    float* Ocomb = (float*)smem;                 // [qh][32 q][stride 68] fp32
    float* Lcomb = (float*)(smem + 17408);       // [qh][32 q]
    if (tp == 1) {
        #pragma unroll
        for (int qg = 0; qg < 2; ++qg) {
            #pragma unroll
            for (int tn = 0; tn < 4; ++tn)
                #pragma unroll
                for (int r = 0; r < 4; ++r)
                    Ocomb[qh * 2176 + (qg * 16 + quad * 4 + r) * 68 + tn * 16 + lm] = oacc[qg][tn][r];
        }
        if (lm == 0) {
            #pragma unroll
            for (int qg = 0; qg < 2; ++qg)
                #pragma unroll
                for (int r = 0; r < 4; ++r)
                    Lcomb[qh * 32 + qg * 16 + quad * 4 + r] = lacc[qg][r];
        }
    }
    __syncthreads();
    if (tp == 0) {
        #pragma unroll
        for (int qg = 0; qg < 2; ++qg) {
            float linv[4];
            #pragma unroll
            for (int r = 0; r < 4; ++r) {
                float lv = __shfl(lacc[qg][r], (lane & 48)) + Lcomb[qh * 32 + qg * 16 + quad * 4 + r];
                linv[r] = 1.0f / lv;
            }
            ushort_t* ob = Ob + ((size_t)(b * SEQ + qw + qg * 16 + quad * 4)) * 512 + h * 64 + lm;
            #pragma unroll
            for (int tn = 0; tn < 4; ++tn)
                #pragma unroll
                for (int r = 0; r < 4; ++r) {
                    float v = oacc[qg][tn][r] + Ocomb[qh * 2176 + (qg * 16 + quad * 4 + r) * 68 + tn * 16 + lm];
                    ob[(size_t)r * 512 + tn * 16] = f2b(v * linv[r]);
                }
        }
    }
}

// ---------------- residual + LayerNorm (x in bf16) ----------------
__global__ __launch_bounds__(256) void ln_kernel(
    const ushort_t* __restrict__ xb, const ushort_t* __restrict__ ob,
    const float* __restrict__ gamma, const float* __restrict__ beta,
    float* __restrict__ out) {

    int row  = blockIdx.x * 4 + (threadIdx.x >> 6);
    int lane = threadIdx.x & 63;

    const ushort_t* xp = xb + (size_t)row * 512 + lane * 8;
    const ushort_t* op = ob + (size_t)row * 512 + lane * 8;

    usx4 xa = ((const usx4*)xp)[0];
    usx4 xc = ((const usx4*)xp)[1];
    usx4 oa = ((const usx4*)op)[0];
    usx4 oc = ((const usx4*)op)[1];
    fx4 va, vb;
    va.x = b2f(xa.x) + b2f(oa.x); va.y = b2f(xa.y) + b2f(oa.y);
    va.z = b2f(xa.z) + b2f(oa.z); va.w = b2f(xa.w) + b2f(oa.w);
    vb.x = b2f(xc.x) + b2f(oc.x); vb.y = b2f(xc.y) + b2f(oc.y);
    vb.z = b2f(xc.z) + b2f(oc.z); vb.w = b2f(xc.w) + b2f(oc.w);

    float s = va.x + va.y + va.z + va.w + vb.x + vb.y + vb.z + vb.w;
    #pragma unroll
    for (int m = 32; m > 0; m >>= 1) s += __shfl_xor(s, m);
    float mu = s * (1.0f / 512.0f);

    fx4 da = va - mu;
    fx4 db = vb - mu;
    float ss = da.x*da.x + da.y*da.y + da.z*da.z + da.w*da.w
             + db.x*db.x + db.y*db.y + db.z*db.z + db.w*db.w;
    #pragma unroll
    for (int m = 32; m > 0; m >>= 1) ss += __shfl_xor(ss, m);
    float rstd = rsqrtf(ss * (1.0f / 512.0f) + 1e-5f);

    const fx4* gp = (const fx4*)(gamma + lane * 8);
    const fx4* bp = (const fx4*)(beta  + lane * 8);
    fx4 g0 = gp[0], g1 = gp[1], b0 = bp[0], b1 = bp[1];

    float* outp = out + (size_t)row * 512 + lane * 8;
    fx4 r0 = da * rstd * g0 + b0;
    fx4 r1 = db * rstd * g1 + b1;
    ((fx4*)outp)[0] = r0;
    ((fx4*)outp)[1] = r1;
}

extern "C" void kernel_launch(void* const* d_in, const int* in_sizes, int n_in,
                              void* d_out, int out_size, void* d_ws, size_t ws_size,
                              hipStream_t stream) {
    const float* val   = (const float*)d_in[0];
    const float* Wq    = (const float*)d_in[1];
    const float* bq    = (const float*)d_in[2];
    const float* Wk    = (const float*)d_in[3];
    const float* bk    = (const float*)d_in[4];
    const float* Wv    = (const float*)d_in[5];
    const float* bv    = (const float*)d_in[6];
    const float* Wo    = (const float*)d_in[7];
    const float* bo    = (const float*)d_in[8];
    const float* gamma = (const float*)d_in[9];
    const float* beta  = (const float*)d_in[10];
    float* out = (float*)d_out;

    char* w = (char*)d_ws;
    ushort_t* xb    = (ushort_t*)w; w += (size_t)ROWS * 512 * 2;
    ushort_t* WqT   = (ushort_t*)w; w += 512 * 512 * 2;
    ushort_t* WkT   = (ushort_t*)w; w += 512 * 512 * 2;
    ushort_t* WvT   = (ushort_t*)w; w += 512 * 512 * 2;
    ushort_t* WoT   = (ushort_t*)w; w += 512 * 512 * 2;
    ushort_t* Qb    = (ushort_t*)w; w += (size_t)ROWS * 512 * 2;
    ushort_t* Kb    = (ushort_t*)w; w += (size_t)ROWS * 512 * 2;
    ushort_t* Vtb   = (ushort_t*)w; w += (size_t)ROWS * 512 * 2;   // [bh][d][s]
    ushort_t* attnb = (ushort_t*)w; w += (size_t)ROWS * 512 * 2;
    ushort_t* obuf  = (ushort_t*)w; w += (size_t)ROWS * 512 * 2;

    prep_kernel<<<dim3(64, 8), 256, 0, stream>>>(
        val, xb, Wq, Wk, Wv, Wo, WqT, WkT, WvT, WoT);

    gemm128_kernel<<<dim3(ROWS / 128, 4, 3), 256, 0, stream>>>(
        xb, WqT, WkT, WvT, bq, bk, bv, Qb, Kb, Vtb);

    attn_mfma_kernel<<<dim3(SEQ / 64, BATCH * NHEAD), 256, 0, stream>>>(Qb, Kb, Vtb, attnb);

    gemm_n64_kernel<<<dim3(ROWS / 128, 8), 256, 0, stream>>>(attnb, WoT, bo, obuf);

    ln_kernel<<<ROWS / 4, 256, 0, stream>>>(xb, obuf, gamma, beta, out);
}

// Round 9
// 160.323 us; speedup vs baseline: 1.1703x; 1.1703x over previous
//
#include <hip/hip_runtime.h>
#include <hip/hip_bf16.h>

// Problem constants
#define BATCH 2
#define SEQ   4096
#define DIM   512
#define NHEAD 8
#define HDIM  64
#define ROWS  (BATCH*SEQ)   // 8192

typedef float  fx4   __attribute__((ext_vector_type(4)));
typedef __bf16 bf16x8 __attribute__((ext_vector_type(8)));
typedef unsigned short ushort_t;
typedef unsigned short usx4 __attribute__((ext_vector_type(4)));
typedef unsigned short usx8 __attribute__((ext_vector_type(8)));

static __device__ __forceinline__ float b2f(ushort_t v) {
    union { unsigned int u; float f; } c; c.u = ((unsigned int)v) << 16; return c.f;
}
static __device__ __forceinline__ ushort_t f2b(float f) {
    union { float f; unsigned int u; } c; c.f = f;
    unsigned int u = c.u;
    unsigned int r = (u + 0x7FFFu + ((u >> 16) & 1u)) >> 16;
    return (ushort_t)r;
}
static __device__ __forceinline__ void gload16(const ushort_t* g, ushort_t* l) {
    __builtin_amdgcn_global_load_lds(
        (const __attribute__((address_space(1))) unsigned int*)g,
        (__attribute__((address_space(3))) unsigned int*)l, 16, 0, 0);
}

// ---------------- prep: transpose 4 weights (y<4) + cast x -> bf16 (y>=4) ----------------
__global__ __launch_bounds__(256) void prep_kernel(
    const float* __restrict__ val, ushort_t* __restrict__ xb,
    const float* __restrict__ W0, const float* __restrict__ W1,
    const float* __restrict__ W2, const float* __restrict__ W3,
    ushort_t* __restrict__ T0, ushort_t* __restrict__ T1,
    ushort_t* __restrict__ T2, ushort_t* __restrict__ T3) {

    const int tid = threadIdx.x;
    if (blockIdx.y >= 4) {
        const int bid = blockIdx.x + 64 * (blockIdx.y - 4);
        const int stride = 256 * 256 * 4;
        for (int i = (bid * 256 + tid) * 4; i < ROWS * 512; i += stride) {
            fx4 v = *(const fx4*)(val + i);
            usx4 o; o.x = f2b(v.x); o.y = f2b(v.y); o.z = f2b(v.z); o.w = f2b(v.w);
            *(usx4*)(xb + i) = o;
        }
        return;
    }
    const float* W; ushort_t* WT;
    switch (blockIdx.y) {
        case 0: W = W0; WT = T0; break;
        case 1: W = W1; WT = T1; break;
        case 2: W = W2; WT = T2; break;
        default: W = W3; WT = T3; break;
    }
    __shared__ float tile[64][65];
    int r0 = (blockIdx.x & 7) * 64;
    int c0 = (blockIdx.x >> 3) * 64;
    for (int idx = tid; idx < 4096; idx += 256) {
        int rr = idx >> 6, cc = idx & 63;
        tile[rr][cc] = W[(c0 + rr) * 512 + (r0 + cc)];
    }
    __syncthreads();
    for (int idx = tid; idx < 4096; idx += 256) {
        int rr = idx >> 6, cc = idx & 63;
        WT[(size_t)(r0 + rr) * 512 + (c0 + cc)] = f2b(tile[cc][rr]);
    }
}

// ---------------- bf16 GEMM (R3-measured-best): C = A @ W + bias ----------------
// 128x128 tile, BK=32, 2-barrier global_load_lds staging, 4 waves 2x2, wave=64x64.
// grid: (M/128, 4, nmat). z==2 writes transposed per head: Vt[bh][d][s].
__global__ __launch_bounds__(256) void gemm128_kernel(
    const ushort_t* __restrict__ A,
    const ushort_t* __restrict__ BT0, const ushort_t* __restrict__ BT1, const ushort_t* __restrict__ BT2,
    const float* __restrict__ b0, const float* __restrict__ b1, const float* __restrict__ b2,
    ushort_t* __restrict__ C0, ushort_t* __restrict__ C1, ushort_t* __restrict__ C2) {

    const ushort_t* BT; const float* bias; ushort_t* C;
    if (blockIdx.z == 0)      { BT = BT0; bias = b0; C = C0; }
    else if (blockIdx.z == 1) { BT = BT1; bias = b1; C = C1; }
    else                      { BT = BT2; bias = b2; C = C2; }

    __shared__ ushort_t As[128 * 32];
    __shared__ ushort_t Bs[128 * 32];

    const int tid  = threadIdx.x;
    const int wave = tid >> 6;
    const int lane = tid & 63;
    const int lm   = lane & 15;
    const int quad = lane >> 4;
    const int wm   = wave >> 1;
    const int wn   = wave & 1;

    const int m0t = blockIdx.x * 128;
    const int n0t = blockIdx.y * 128;

    const int srow = tid >> 2, sgc = tid & 3;
    const ushort_t* ga0 = A  + (size_t)(m0t + srow) * 512 + sgc * 8;
    const ushort_t* ga1 = ga0 + (size_t)64 * 512;
    const ushort_t* gb0 = BT + (size_t)(n0t + srow) * 512 + sgc * 8;
    const ushort_t* gb1 = gb0 + (size_t)64 * 512;
    ushort_t* la0 = As + tid * 8;
    ushort_t* la1 = As + (tid + 256) * 8;
    ushort_t* lb0 = Bs + tid * 8;
    ushort_t* lb1 = Bs + (tid + 256) * 8;

    const int aoff = (wm * 64 + lm) * 32 + quad * 8;
    const int boff = (wn * 64 + lm) * 32 + quad * 8;

    fx4 acc[4][4];
    #pragma unroll
    for (int i = 0; i < 4; ++i)
        #pragma unroll
        for (int j = 0; j < 4; ++j) acc[i][j] = 0;

    for (int k0 = 0; k0 < 512; k0 += 32) {
        __syncthreads();
        gload16(ga0 + k0, la0);
        gload16(ga1 + k0, la1);
        gload16(gb0 + k0, lb0);
        gload16(gb1 + k0, lb1);
        __syncthreads();

        bf16x8 af[4], bfr[4];
        #pragma unroll
        for (int ms = 0; ms < 4; ++ms) af[ms]  = *(const bf16x8*)&As[aoff + ms * 512];
        #pragma unroll
        for (int ns = 0; ns < 4; ++ns) bfr[ns] = *(const bf16x8*)&Bs[boff + ns * 512];
        #pragma unroll
        for (int ms = 0; ms < 4; ++ms)
            #pragma unroll
            for (int ns = 0; ns < 4; ++ns)
                acc[ms][ns] = __builtin_amdgcn_mfma_f32_16x16x32_bf16(af[ms], bfr[ns], acc[ms][ns], 0, 0, 0);
    }

    const int crow0 = m0t + wm * 64 + quad * 4;
    const int ccol0 = n0t + wn * 64 + lm;

    if (blockIdx.z == 2) {
        #pragma unroll
        for (int ns = 0; ns < 4; ++ns) {
            int col = ccol0 + ns * 16;
            int h = col >> 6, d = col & 63;
            float bv = bias[col];
            #pragma unroll
            for (int ms = 0; ms < 4; ++ms) {
                int m = crow0 + ms * 16;
                int bb = m >> 12, s0 = m & 4095;
                usx4 o;
                o.x = f2b(acc[ms][ns][0] + bv); o.y = f2b(acc[ms][ns][1] + bv);
                o.z = f2b(acc[ms][ns][2] + bv); o.w = f2b(acc[ms][ns][3] + bv);
                *(usx4*)(C + (((size_t)(bb * 8 + h) * 64 + d) * 4096 + s0)) = o;
            }
        }
    } else {
        #pragma unroll
        for (int ns = 0; ns < 4; ++ns) {
            int col = ccol0 + ns * 16;
            float bv = bias[col];
            #pragma unroll
            for (int ms = 0; ms < 4; ++ms) {
                #pragma unroll
                for (int r = 0; r < 4; ++r) {
                    C[(size_t)(crow0 + ms * 16 + r) * 512 + col] = f2b(acc[ms][ns][r] + bv);
                }
            }
        }
    }
}

// ---------------- MFMA sliding-window attention (radius 256) ----------------
// grid: 1024 1-D blocks, 256 threads = 4 waves, 16 q/wave (R7-measured-best),
// plus XCD-aware swizzle: hardware round-robins sequential workgroups across
// 8 XCDs, so remap l=(wg&7)*128+(wg>>3) to give each XCD 128 logically
// consecutive (bh, q0) blocks -> the 9x K/V tile reuse stays in one L2.
__global__ __launch_bounds__(256, 4) void attn_mfma_kernel(
    const ushort_t* __restrict__ Qb, const ushort_t* __restrict__ Kb,
    const ushort_t* __restrict__ Vt, ushort_t* __restrict__ Ob) {

    __shared__ ushort_t Klds[64 * 64];     // [key][d], granule-XOR swizzle
    __shared__ ushort_t Vlds[64 * 64];     // [d][key], granule-XOR swizzle
    __shared__ ushort_t Plds[4 * 16 * 72]; // per-wave [16 q][64 key], stride 72

    const int tid  = threadIdx.x;
    const int wave = tid >> 6;
    const int lane = tid & 63;
    const int lm   = lane & 15;
    const int quad = lane >> 4;

    const int wg = blockIdx.x;
    const int l  = (wg & 7) * 128 + (wg >> 3);   // XCD-contiguous logical id
    const int bh = l >> 6;
    const int b = bh >> 3, h = bh & 7;
    const int q0 = (l & 63) * 64;
    const int qw = q0 + wave * 16;

    // Q fragment (lane=lm -> q, quad over d) — MFMA B operand for S^T
    const ushort_t* qp = Qb + ((size_t)(b * SEQ + qw + lm)) * 512 + h * 64 + quad * 8;
    bf16x8 qf0 = *(const bf16x8*)qp;
    bf16x8 qf1 = *(const bf16x8*)(qp + 32);

    int koff[2][4], voff[2][4];
    #pragma unroll
    for (int ks = 0; ks < 2; ++ks) {
        #pragma unroll
        for (int tn = 0; tn < 4; ++tn) {
            int key = tn * 16 + lm;
            koff[ks][tn] = key * 64 + (((ks * 4 + quad) ^ (key & 7)) * 8);
            int d = tn * 16 + lm;
            voff[ks][tn] = d * 64 + (((ks * 4 + quad) ^ (d & 7)) * 8);
        }
    }
    ushort_t* Pw = Plds + wave * (16 * 72);
    const int pwbase = lm * 72 + quad * 4;   // P write: packed b64
    const int prbase = lm * 72 + quad * 8;   // P read: b128 A-frag

    const int skey = tid >> 3;
    const int sdg  = tid & 7;
    const size_t kgbase = ((size_t)b * SEQ) * 512 + h * 64 + sdg * 8;
    const size_t vgbase = ((size_t)bh * 64) * 4096 + sdg * 8;
    const int l0 = skey * 64 + ((sdg ^ (skey & 7)) * 8);
    const int l1 = l0 + 32 * 64;

    const int klo = (q0 >= 256) ? 0 : ((256 - q0) >> 6);
    const int khi = min(8, (4288 - q0) >> 6);

    bf16x8 onesf;
    {
        __bf16 o = (lm == 0) ? (__bf16)1.0f : (__bf16)0.0f;
        #pragma unroll
        for (int j = 0; j < 8; ++j) onesf[j] = o;
    }

    fx4 oacc[4];
    oacc[0] = 0; oacc[1] = 0; oacc[2] = 0; oacc[3] = 0;
    fx4 lacc = 0;

    usx8 kn0, kn1, vn0, vn1;
    {
        int ts = q0 - 256 + klo * 64;
        kn0 = *(const usx8*)(Kb + kgbase + (size_t)(ts + skey) * 512);
        kn1 = *(const usx8*)(Kb + kgbase + (size_t)(ts + skey + 32) * 512);
        vn0 = *(const usx8*)(Vt + vgbase + (size_t)skey * 4096 + ts);
        vn1 = *(const usx8*)(Vt + vgbase + (size_t)(skey + 32) * 4096 + ts);
    }

    for (int kt = klo; kt <= khi; ++kt) {
        const int ts = q0 - 256 + kt * 64;
        __syncthreads();
        *(usx8*)&Klds[l0] = kn0;
        *(usx8*)&Klds[l1] = kn1;
        *(usx8*)&Vlds[l0] = vn0;
        *(usx8*)&Vlds[l1] = vn1;
        __syncthreads();

        if (kt < khi) {   // prefetch next tile during compute
            int t2 = ts + 64;
            kn0 = *(const usx8*)(Kb + kgbase + (size_t)(t2 + skey) * 512);
            kn1 = *(const usx8*)(Kb + kgbase + (size_t)(t2 + skey + 32) * 512);
            vn0 = *(const usx8*)(Vt + vgbase + (size_t)skey * 4096 + t2);
            vn1 = *(const usx8*)(Vt + vgbase + (size_t)(skey + 32) * 4096 + t2);
        }

        // S^T = K (64 keys) @ Q^T (16 q): rows=keys, cols=q
        bf16x8 kf[2][4];
        #pragma unroll
        for (int ks = 0; ks < 2; ++ks)
            #pragma unroll
            for (int tn = 0; tn < 4; ++tn)
                kf[ks][tn] = *(const bf16x8*)&Klds[koff[ks][tn]];
        fx4 sacc[4];
        sacc[0] = 0; sacc[1] = 0; sacc[2] = 0; sacc[3] = 0;
        #pragma unroll
        for (int ks = 0; ks < 2; ++ks) {
            bf16x8 q8 = ks ? qf1 : qf0;
            #pragma unroll
            for (int tn = 0; tn < 4; ++tn)
                sacc[tn] = __builtin_amdgcn_mfma_f32_16x16x32_bf16(kf[ks][tn], q8, sacc[tn], 0, 0, 0);
        }

        // P^T rows are keys: lane owns 4 consecutive keys per tn -> packed b64 write
        const bool edge = (ts < qw - 241) || (ts > qw + 193);
        const int qg = qw + lm;
        #pragma unroll
        for (int tn = 0; tn < 4; ++tn) {
            usx4 pk;
            #pragma unroll
            for (int r = 0; r < 4; ++r) {
                float p = __expf(sacc[tn][r] * 0.125f);
                if (edge) {
                    int dlt = (ts + tn * 16 + quad * 4 + r) - qg;
                    p = (dlt <= 256 && dlt >= -256) ? p : 0.0f;
                }
                pk[r] = f2b(p);
            }
            *(usx4*)&Pw[pwbase + tn * 16] = pk;
        }

        // O += P @ V ; l += P @ ones
        bf16x8 vf[2][4];
        #pragma unroll
        for (int ks = 0; ks < 2; ++ks)
            #pragma unroll
            for (int tn = 0; tn < 4; ++tn)
                vf[ks][tn] = *(const bf16x8*)&Vlds[voff[ks][tn]];
        #pragma unroll
        for (int ks = 0; ks < 2; ++ks) {
            bf16x8 ap = *(const bf16x8*)&Pw[prbase + ks * 32];
            lacc = __builtin_amdgcn_mfma_f32_16x16x32_bf16(ap, onesf, lacc, 0, 0, 0);
            #pragma unroll
            for (int tn = 0; tn < 4; ++tn)
                oacc[tn] = __builtin_amdgcn_mfma_f32_16x16x32_bf16(ap, vf[ks][tn], oacc[tn], 0, 0, 0);
        }
    }

    float linv[4];
    #pragma unroll
    for (int r = 0; r < 4; ++r) {
        float lv = __shfl(lacc[r], (lane & 48));
        linv[r] = 1.0f / lv;
    }
    ushort_t* ob = Ob + ((size_t)(b * SEQ + qw + quad * 4)) * 512 + h * 64 + lm;
    #pragma unroll
    for (int tn = 0; tn < 4; ++tn)
        #pragma unroll
        for (int r = 0; r < 4; ++r)
            ob[(size_t)r * 512 + tn * 16] = f2b(oacc[tn][r] * linv[r]);
}

// ---------------- residual + LayerNorm (x in bf16) ----------------
__global__ __launch_bounds__(256) void ln_kernel(
    const ushort_t* __restrict__ xb, const ushort_t* __restrict__ ob,
    const float* __restrict__ gamma, const float* __restrict__ beta,
    float* __restrict__ out) {

    int row  = blockIdx.x * 4 + (threadIdx.x >> 6);
    int lane = threadIdx.x & 63;

    const ushort_t* xp = xb + (size_t)row * 512 + lane * 8;
    const ushort_t* op = ob + (size_t)row * 512 + lane * 8;

    usx4 xa = ((const usx4*)xp)[0];
    usx4 xc = ((const usx4*)xp)[1];
    usx4 oa = ((const usx4*)op)[0];
    usx4 oc = ((const usx4*)op)[1];
    fx4 va, vb;
    va.x = b2f(xa.x) + b2f(oa.x); va.y = b2f(xa.y) + b2f(oa.y);
    va.z = b2f(xa.z) + b2f(oa.z); va.w = b2f(xa.w) + b2f(oa.w);
    vb.x = b2f(xc.x) + b2f(oc.x); vb.y = b2f(xc.y) + b2f(oc.y);
    vb.z = b2f(xc.z) + b2f(oc.z); vb.w = b2f(xc.w) + b2f(oc.w);

    float s = va.x + va.y + va.z + va.w + vb.x + vb.y + vb.z + vb.w;
    #pragma unroll
    for (int m = 32; m > 0; m >>= 1) s += __shfl_xor(s, m);
    float mu = s * (1.0f / 512.0f);

    fx4 da = va - mu;
    fx4 db = vb - mu;
    float ss = da.x*da.x + da.y*da.y + da.z*da.z + da.w*da.w
             + db.x*db.x + db.y*db.y + db.z*db.z + db.w*db.w;
    #pragma unroll
    for (int m = 32; m > 0; m >>= 1) ss += __shfl_xor(ss, m);
    float rstd = rsqrtf(ss * (1.0f / 512.0f) + 1e-5f);

    const fx4* gp = (const fx4*)(gamma + lane * 8);
    const fx4* bp = (const fx4*)(beta  + lane * 8);
    fx4 g0 = gp[0], g1 = gp[1], b0 = bp[0], b1 = bp[1];

    float* outp = out + (size_t)row * 512 + lane * 8;
    fx4 r0 = da * rstd * g0 + b0;
    fx4 r1 = db * rstd * g1 + b1;
    ((fx4*)outp)[0] = r0;
    ((fx4*)outp)[1] = r1;
}

extern "C" void kernel_launch(void* const* d_in, const int* in_sizes, int n_in,
                              void* d_out, int out_size, void* d_ws, size_t ws_size,
                              hipStream_t stream) {
    const float* val   = (const float*)d_in[0];
    const float* Wq    = (const float*)d_in[1];
    const float* bq    = (const float*)d_in[2];
    const float* Wk    = (const float*)d_in[3];
    const float* bk    = (const float*)d_in[4];
    const float* Wv    = (const float*)d_in[5];
    const float* bv    = (const float*)d_in[6];
    const float* Wo    = (const float*)d_in[7];
    const float* bo    = (const float*)d_in[8];
    const float* gamma = (const float*)d_in[9];
    const float* beta  = (const float*)d_in[10];
    float* out = (float*)d_out;

    char* w = (char*)d_ws;
    ushort_t* xb    = (ushort_t*)w; w += (size_t)ROWS * 512 * 2;
    ushort_t* WqT   = (ushort_t*)w; w += 512 * 512 * 2;
    ushort_t* WkT   = (ushort_t*)w; w += 512 * 512 * 2;
    ushort_t* WvT   = (ushort_t*)w; w += 512 * 512 * 2;
    ushort_t* WoT   = (ushort_t*)w; w += 512 * 512 * 2;
    ushort_t* Qb    = (ushort_t*)w; w += (size_t)ROWS * 512 * 2;
    ushort_t* Kb    = (ushort_t*)w; w += (size_t)ROWS * 512 * 2;
    ushort_t* Vtb   = (ushort_t*)w; w += (size_t)ROWS * 512 * 2;   // [bh][d][s]
    ushort_t* attnb = (ushort_t*)w; w += (size_t)ROWS * 512 * 2;
    ushort_t* obuf  = (ushort_t*)w; w += (size_t)ROWS * 512 * 2;

    prep_kernel<<<dim3(64, 8), 256, 0, stream>>>(
        val, xb, Wq, Wk, Wv, Wo, WqT, WkT, WvT, WoT);

    gemm128_kernel<<<dim3(ROWS / 128, 4, 3), 256, 0, stream>>>(
        xb, WqT, WkT, WvT, bq, bk, bv, Qb, Kb, Vtb);

    attn_mfma_kernel<<<1024, 256, 0, stream>>>(Qb, Kb, Vtb, attnb);

    gemm128_kernel<<<dim3(ROWS / 128, 4, 1), 256, 0, stream>>>(
        attnb, WoT, WoT, WoT, bo, bo, bo, obuf, obuf, obuf);

    ln_kernel<<<ROWS / 4, 256, 0, stream>>>(xb, obuf, gamma, beta, out);
}